// Round 2
// baseline (10502.920 us; speedup 1.0000x reference)
//
#include <hip/hip_runtime.h>

#define NB 4
#define NM 80
#define NT 65536
#define NR 64
#define ND 64
#define NS 64
#define NL 20

__device__ __forceinline__ float fast_tanh(float v) {
    // tanh(v) = 1 - 2/(exp(2v)+1); exact saturation at +-inf, ~1e-7 rel error
    float e = __expf(2.0f * v);
    return 1.0f - 2.0f / (e + 1.0f);
}

extern "C" __global__ void __launch_bounds__(256)
__attribute__((amdgpu_waves_per_eu(2, 2)))
wavenet_fp32_kernel(const float* __restrict__ x,
                    const float* __restrict__ wc, const float* __restrict__ bc,
                    const float* __restrict__ wd, const float* __restrict__ bd,
                    const float* __restrict__ wr, const float* __restrict__ br,
                    const float* __restrict__ ws, const float* __restrict__ bs,
                    const float* __restrict__ w1, const float* __restrict__ b1,
                    const float* __restrict__ w2, const float* __restrict__ b2,
                    float* __restrict__ out)
{
    const int col = blockIdx.x * 256 + threadIdx.x;   // 0 .. B*T-1
    const int b   = col >> 16;                        // T = 65536
    const int t   = col & (NT - 1);
    const float* xc = x + ((size_t)b * NM) * NT + t;  // x[b][m][t] = xc[m*NT]

    // ---- causal 1x1 conv: h[r] = bc[r] + sum_m wc[r][m] * x[m] ----
    float h[NR];
#pragma unroll
    for (int r = 0; r < NR; ++r) h[r] = bc[r];

#pragma unroll
    for (int mt = 0; mt < NM; mt += 16) {
        float xv[16];
#pragma unroll
        for (int i = 0; i < 16; ++i)
            xv[i] = xc[(size_t)(mt + i) * NT];
#pragma unroll
        for (int r = 0; r < NR; r += 8) {
            float acc[8];
#pragma unroll
            for (int j = 0; j < 8; ++j) acc[j] = h[r + j];
#pragma unroll
            for (int i = 0; i < 16; ++i) {
                const float xvv = xv[i];
#pragma unroll
                for (int j = 0; j < 8; ++j)
                    acc[j] = fmaf(wc[(r + j) * NM + mt + i], xvv, acc[j]);
            }
#pragma unroll
            for (int j = 0; j < 8; ++j) h[r + j] = acc[j];
        }
    }

    float skip[NS];
#pragma unroll
    for (int s = 0; s < NS; ++s) skip[s] = 0.0f;

    // ---- 20 residual layers (layer loop rolled; inner loops unrolled) ----
    for (int l = 0; l < NL; ++l) {
        const float* wdl = wd + (size_t)l * ND * NR;
        const float* bdl = bd + (size_t)l * ND;
        const float* wrl = wr + (size_t)l * NR * ND;
        const float* brl = br + (size_t)l * NR;
        const float* wsl = ws + (size_t)l * NS * ND;
        const float* bsl = bs + (size_t)l * NS;

        // f[d] = tanh(bd[d] + sum_r wd[d][r] * h[r])
        float f[ND];
#pragma unroll
        for (int d = 0; d < ND; d += 8) {
            float acc[8];
#pragma unroll
            for (int j = 0; j < 8; ++j) acc[j] = bdl[d + j];
#pragma unroll
            for (int r = 0; r < NR; ++r) {
                const float hv = h[r];
#pragma unroll
                for (int j = 0; j < 8; ++j)
                    acc[j] = fmaf(wdl[(d + j) * NR + r], hv, acc[j]);
            }
#pragma unroll
            for (int j = 0; j < 8; ++j) f[d + j] = fast_tanh(acc[j]);
        }

        // skip[s] += bs[s] + sum_d ws[s][d] * f[d]
#pragma unroll
        for (int s = 0; s < NS; s += 8) {
            float acc[8];
#pragma unroll
            for (int j = 0; j < 8; ++j) acc[j] = 0.0f;
#pragma unroll
            for (int d = 0; d < ND; ++d) {
                const float fv = f[d];
#pragma unroll
                for (int j = 0; j < 8; ++j)
                    acc[j] = fmaf(wsl[(s + j) * ND + d], fv, acc[j]);
            }
#pragma unroll
            for (int j = 0; j < 8; ++j)
                skip[s + j] += acc[j] + bsl[s + j];
        }

        // h[r] += br[r] + sum_d wr[r][d] * f[d]
#pragma unroll
        for (int r = 0; r < NR; r += 8) {
            float acc[8];
#pragma unroll
            for (int j = 0; j < 8; ++j) acc[j] = 0.0f;
#pragma unroll
            for (int d = 0; d < ND; ++d) {
                const float fv = f[d];
#pragma unroll
                for (int j = 0; j < 8; ++j)
                    acc[j] = fmaf(wrl[(r + j) * ND + d], fv, acc[j]);
            }
#pragma unroll
            for (int j = 0; j < 8; ++j)
                h[r + j] += acc[j] + brl[r + j];
        }
    }

    // ---- post net ----
#pragma unroll
    for (int s = 0; s < NS; ++s) skip[s] = fast_tanh(skip[s]);

    // s2 = tanh(w1 @ s + b1)
    float s2[NS];
#pragma unroll
    for (int o = 0; o < NS; o += 8) {
        float acc[8];
#pragma unroll
        for (int j = 0; j < 8; ++j) acc[j] = b1[o + j];
#pragma unroll
        for (int s = 0; s < NS; ++s) {
            const float sv = skip[s];
#pragma unroll
            for (int j = 0; j < 8; ++j)
                acc[j] = fmaf(w1[(o + j) * NS + s], sv, acc[j]);
        }
#pragma unroll
        for (int j = 0; j < 8; ++j) s2[o + j] = fast_tanh(acc[j]);
    }

    // out = w2 @ s2 + b2   (single output channel)
    float p0 = 0.0f, p1 = 0.0f, p2 = 0.0f, p3 = 0.0f;
#pragma unroll
    for (int s = 0; s < NS; s += 4) {
        p0 = fmaf(w2[s + 0], s2[s + 0], p0);
        p1 = fmaf(w2[s + 1], s2[s + 1], p1);
        p2 = fmaf(w2[s + 2], s2[s + 2], p2);
        p3 = fmaf(w2[s + 3], s2[s + 3], p3);
    }
    out[col] = b2[0] + ((p0 + p1) + (p2 + p3));
}

extern "C" void kernel_launch(void* const* d_in, const int* in_sizes, int n_in,
                              void* d_out, int out_size, void* d_ws, size_t ws_size,
                              hipStream_t stream) {
    const float* x  = (const float*)d_in[0];
    const float* wc = (const float*)d_in[1];
    const float* bc = (const float*)d_in[2];
    const float* wd = (const float*)d_in[3];
    const float* bd = (const float*)d_in[4];
    const float* wr = (const float*)d_in[5];
    const float* br = (const float*)d_in[6];
    const float* ws = (const float*)d_in[7];
    const float* bs = (const float*)d_in[8];
    const float* w1 = (const float*)d_in[9];
    const float* b1 = (const float*)d_in[10];
    const float* w2 = (const float*)d_in[11];
    const float* b2 = (const float*)d_in[12];
    float* out = (float*)d_out;

    dim3 grid((NB * NT) / 256);
    dim3 block(256);
    hipLaunchKernelGGL(wavenet_fp32_kernel, grid, block, 0, stream,
                       x, wc, bc, wd, bd, wr, br, ws, bs, w1, b1, w2, b2, out);
}

// Round 3
// 1059.221 us; speedup vs baseline: 9.9157x; 9.9157x over previous
//
#include <hip/hip_runtime.h>

#define NB 4
#define NM 80
#define NT 65536
#define NL 20

// ---------- types (may_alias: all LDS/global reinterpret casts go through these) ----------
typedef __bf16 bf16x8 __attribute__((ext_vector_type(8), may_alias));
typedef float f32x4 __attribute__((ext_vector_type(4), may_alias));
typedef unsigned int u32x2 __attribute__((ext_vector_type(2), may_alias));
typedef unsigned int u32x4 __attribute__((ext_vector_type(4), may_alias));

// ---------- d_ws layout (ushort units): pre-split weight planes ----------
#define WCHI 0
#define WCLO 6144
#define WDHI 12288
#define WDLO 94208
#define WSHI 176128
#define WSLO 258048
#define WRHI 339968
#define WRLO 421888
#define W1HI 503808
#define W1LO 507904
#define WTOT 512000

// ---------- LDS byte offsets (64 KiB total; x planes alias h/f planes) ----------
#define XHI_O 0
#define XLO_O 24576
#define HHI_O 0
#define HLO_O 16384
#define FHI_O 32768
#define FLO_O 49152

__device__ __forceinline__ unsigned f2u(float x) { return __float_as_uint(x); }
__device__ __forceinline__ float u2f(unsigned u) { return __uint_as_float(u); }
// pack bf16(a) (truncated) into low half, bf16(b) into high half
__device__ __forceinline__ unsigned pack2(float a, float b) {
    return (f2u(a) >> 16) | (f2u(b) & 0xffff0000u);
}
__device__ __forceinline__ float fast_tanh(float v) {
    float e = __expf(2.0f * v);
    return 1.0f - 2.0f / (e + 1.0f);
}
__device__ __forceinline__ f32x4 mm3(bf16x8 ah, bf16x8 al, bf16x8 bh, bf16x8 bl, f32x4 c) {
    c = __builtin_amdgcn_mfma_f32_16x16x32_bf16(ah, bh, c, 0, 0, 0);
    c = __builtin_amdgcn_mfma_f32_16x16x32_bf16(ah, bl, c, 0, 0, 0);
    c = __builtin_amdgcn_mfma_f32_16x16x32_bf16(al, bh, c, 0, 0, 0);
    return c;
}
// split 4 fp32 into (hi,lo) bf16 pairs, packed 2-per-dword in k-ascending order
__device__ __forceinline__ void split_pack(f32x4 v, u32x2& hi, u32x2& lo) {
    float l0 = v[0] - u2f(f2u(v[0]) & 0xffff0000u);
    float l1 = v[1] - u2f(f2u(v[1]) & 0xffff0000u);
    float l2 = v[2] - u2f(f2u(v[2]) & 0xffff0000u);
    float l3 = v[3] - u2f(f2u(v[3]) & 0xffff0000u);
    hi[0] = pack2(v[0], v[1]);
    hi[1] = pack2(v[2], v[3]);
    lo[0] = pack2(l0, l1);
    lo[1] = pack2(l2, l3);
}
// reconstruct 4 fp32 = hi + lo from packed planes
__device__ __forceinline__ f32x4 unpack_add(u32x2 a, u32x2 b) {
    f32x4 r;
    r[0] = u2f(a[0] << 16) + u2f(b[0] << 16);
    r[1] = u2f(a[0] & 0xffff0000u) + u2f(b[0] & 0xffff0000u);
    r[2] = u2f(a[1] << 16) + u2f(b[1] << 16);
    r[3] = u2f(a[1] & 0xffff0000u) + u2f(b[1] & 0xffff0000u);
    return r;
}

// ---------- prep: split all weights into bf16 hi/lo planes in d_ws ----------
extern "C" __global__ void __launch_bounds__(256)
wavenet_prep(const float* __restrict__ wc, const float* __restrict__ wd,
             const float* __restrict__ wsk, const float* __restrict__ wr,
             const float* __restrict__ w1, unsigned short* __restrict__ o)
{
    int i = blockIdx.x * 256 + threadIdx.x;
    if (i >= 256000) return;
    float v;
    int hi, lo, idx;
    if (i < 6144) {                       // wc: [64][80] -> padded [64][96]
        idx = i;
        int r = i / 96, m = i % 96;
        v = (m < NM) ? wc[r * NM + m] : 0.0f;
        hi = WCHI; lo = WCLO;
    } else if (i < 88064) {               // wd: [20][64][64]
        idx = i - 6144; v = wd[idx]; hi = WDHI; lo = WDLO;
    } else if (i < 169984) {              // ws: [20][64][64]
        idx = i - 88064; v = wsk[idx]; hi = WSHI; lo = WSLO;
    } else if (i < 251904) {              // wr: [20][64][64]
        idx = i - 169984; v = wr[idx]; hi = WRHI; lo = WRLO;
    } else {                              // w1: [64][64]
        idx = i - 251904; v = w1[idx]; hi = W1HI; lo = W1LO;
    }
    unsigned uh = f2u(v) & 0xffff0000u;
    float rem = v - u2f(uh);
    o[hi + idx] = (unsigned short)(uh >> 16);
    o[lo + idx] = (unsigned short)(f2u(rem) >> 16);
}

// ---------- main kernel ----------
extern "C" __global__ void __launch_bounds__(256)
wavenet_mfma(const float* __restrict__ x, const float* __restrict__ bc,
             const float* __restrict__ bd, const float* __restrict__ br,
             const float* __restrict__ bs, const float* __restrict__ b1,
             const float* __restrict__ w2, const float* __restrict__ b2,
             const unsigned short* __restrict__ wsu, float* __restrict__ out)
{
    __shared__ __align__(16) unsigned char smem[65536];

    const int tid = threadIdx.x;
    const int wave = tid >> 6;
    const int lane = tid & 63;
    const int q = lane >> 4;       // lane quarter-group
    const int c16 = lane & 15;     // col within 16-wide n-tile
    const int wcol0 = wave * 32;   // this wave's 32 columns within the tile

    const int gcol0 = blockIdx.x * 128;
    const int bidx = gcol0 >> 16;          // T = 65536
    const int t0 = gcol0 & (NT - 1);

    // ================= stage x into LDS hi/lo planes [col][96 k] (stride 192B) =================
    {
        const int scol = wcol0 + (lane & 31);
        const int half = lane >> 5;
        const float* xcp = x + (size_t)bidx * NM * NT + t0 + scol;
        unsigned char* xh = smem + XHI_O + scol * 192;
        unsigned char* xl = smem + XLO_O + scol * 192;
#pragma unroll
        for (int hh = 0; hh < 6; ++hh) {
            int oct = half * 6 + hh;
            u32x4 ph, pl;
#pragma unroll
            for (int jj = 0; jj < 4; ++jj) {
                int r0 = oct * 8 + 2 * jj;
                float a = (r0 < NM) ? xcp[(size_t)r0 * NT] : 0.0f;
                float bfv = (r0 + 1 < NM) ? xcp[(size_t)(r0 + 1) * NT] : 0.0f;
                float la = a - u2f(f2u(a) & 0xffff0000u);
                float lb = bfv - u2f(f2u(bfv) & 0xffff0000u);
                ph[jj] = pack2(a, bfv);
                pl[jj] = pack2(la, lb);
            }
            *(u32x4*)(xh + oct * 16) = ph;
            *(u32x4*)(xl + oct * 16) = pl;
        }
    }
    // no barrier needed: each wave reads only its own columns

    // ================= causal conv: h = Wc @ x + bc  (K=96, zero-padded) =================
    f32x4 hD[4][2];
#pragma unroll
    for (int m = 0; m < 4; ++m) {
        bf16x8 Ah[3], Al[3];
#pragma unroll
        for (int ks = 0; ks < 3; ++ks) {
            Ah[ks] = *(const bf16x8*)(wsu + WCHI + (m * 16 + c16) * 96 + ks * 32 + q * 8);
            Al[ks] = *(const bf16x8*)(wsu + WCLO + (m * 16 + c16) * 96 + ks * 32 + q * 8);
        }
        f32x4 bc4 = *(const f32x4*)(bc + m * 16 + q * 4);
#pragma unroll
        for (int nt = 0; nt < 2; ++nt) {
            const int colL = wcol0 + nt * 16 + c16;
            f32x4 acc = bc4;
#pragma unroll
            for (int ks = 0; ks < 3; ++ks) {
                bf16x8 Bh = *(const bf16x8*)(smem + XHI_O + colL * 192 + (ks * 4 + q) * 16);
                bf16x8 Bl = *(const bf16x8*)(smem + XLO_O + colL * 192 + (ks * 4 + q) * 16);
                acc = mm3(Ah[ks], Al[ks], Bh, Bl, acc);
            }
            hD[m][nt] = acc;
        }
    }

    // all x reads done; h planes alias x region across waves -> one barrier
    __syncthreads();

    // write h planes [col][64 k] (stride 128B, XOR-octet swizzle)
#pragma unroll
    for (int m = 0; m < 4; ++m) {
#pragma unroll
        for (int nt = 0; nt < 2; ++nt) {
            const int colL = wcol0 + nt * 16 + c16;
            u32x2 ph, pl;
            split_pack(hD[m][nt], ph, pl);
            const int wb = colL * 128 + (((m * 2 + (q >> 1)) ^ (colL & 7)) * 16) + (q & 1) * 8;
            *(u32x2*)(smem + HHI_O + wb) = ph;
            *(u32x2*)(smem + HLO_O + wb) = pl;
        }
    }

    // persistent skip accumulators (MFMA C-layout), biases folded in at the end
    f32x4 skipacc[4][2];
#pragma unroll
    for (int m = 0; m < 4; ++m)
#pragma unroll
        for (int nt = 0; nt < 2; ++nt)
            skipacc[m][nt] = (f32x4){0.f, 0.f, 0.f, 0.f};

    // ================= 20 residual layers =================
#pragma unroll 1
    for (int l = 0; l < NL; ++l) {
        const unsigned short* wdh = wsu + WDHI + l * 4096;
        const unsigned short* wdl = wsu + WDLO + l * 4096;
        const unsigned short* wsh = wsu + WSHI + l * 4096;
        const unsigned short* wsl = wsu + WSLO + l * 4096;
        const unsigned short* wrh = wsu + WRHI + l * 4096;
        const unsigned short* wrl = wsu + WRLO + l * 4096;
        const float* bdl = bd + l * 64;
        const float* brl = br + l * 64;

        // ---- B-fragments of h (own cols) ----
        bf16x8 Hh[2][2], Hl[2][2];
#pragma unroll
        for (int nt = 0; nt < 2; ++nt) {
            const int colL = wcol0 + nt * 16 + c16;
#pragma unroll
            for (int ks = 0; ks < 2; ++ks) {
                const int sw = colL * 128 + (((ks * 4 + q) ^ (colL & 7)) * 16);
                Hh[nt][ks] = *(const bf16x8*)(smem + HHI_O + sw);
                Hl[nt][ks] = *(const bf16x8*)(smem + HLO_O + sw);
            }
        }

        // ---- phase D: f = tanh(Wd h + bd), write f planes ----
#pragma unroll
        for (int m = 0; m < 4; ++m) {
            bf16x8 Ah[2], Al[2];
#pragma unroll
            for (int ks = 0; ks < 2; ++ks) {
                Ah[ks] = *(const bf16x8*)(wdh + (m * 16 + c16) * 64 + ks * 32 + q * 8);
                Al[ks] = *(const bf16x8*)(wdl + (m * 16 + c16) * 64 + ks * 32 + q * 8);
            }
            f32x4 bd4 = *(const f32x4*)(bdl + m * 16 + q * 4);
#pragma unroll
            for (int nt = 0; nt < 2; ++nt) {
                f32x4 acc = bd4;
#pragma unroll
                for (int ks = 0; ks < 2; ++ks)
                    acc = mm3(Ah[ks], Al[ks], Hh[nt][ks], Hl[nt][ks], acc);
                f32x4 f;
#pragma unroll
                for (int i = 0; i < 4; ++i) f[i] = fast_tanh(acc[i]);
                const int colL = wcol0 + nt * 16 + c16;
                u32x2 ph, pl;
                split_pack(f, ph, pl);
                const int wb = colL * 128 + (((m * 2 + (q >> 1)) ^ (colL & 7)) * 16) + (q & 1) * 8;
                *(u32x2*)(smem + FHI_O + wb) = ph;
                *(u32x2*)(smem + FLO_O + wb) = pl;
            }
        }

        // ---- B-fragments of f (own cols; written above by this wave) ----
        bf16x8 Fh[2][2], Fl[2][2];
#pragma unroll
        for (int nt = 0; nt < 2; ++nt) {
            const int colL = wcol0 + nt * 16 + c16;
#pragma unroll
            for (int ks = 0; ks < 2; ++ks) {
                const int sw = colL * 128 + (((ks * 4 + q) ^ (colL & 7)) * 16);
                Fh[nt][ks] = *(const bf16x8*)(smem + FHI_O + sw);
                Fl[nt][ks] = *(const bf16x8*)(smem + FLO_O + sw);
            }
        }

        // ---- phase S: skip += Ws f (bias folded later) ----
#pragma unroll
        for (int m = 0; m < 4; ++m) {
            bf16x8 Ah[2], Al[2];
#pragma unroll
            for (int ks = 0; ks < 2; ++ks) {
                Ah[ks] = *(const bf16x8*)(wsh + (m * 16 + c16) * 64 + ks * 32 + q * 8);
                Al[ks] = *(const bf16x8*)(wsl + (m * 16 + c16) * 64 + ks * 32 + q * 8);
            }
#pragma unroll
            for (int nt = 0; nt < 2; ++nt) {
#pragma unroll
                for (int ks = 0; ks < 2; ++ks)
                    skipacc[m][nt] = mm3(Ah[ks], Al[ks], Fh[nt][ks], Fl[nt][ks], skipacc[m][nt]);
            }
        }

        // ---- phase R: h = h + Wr f + br (C-init from h planes, write back) ----
#pragma unroll
        for (int m = 0; m < 4; ++m) {
            bf16x8 Ah[2], Al[2];
#pragma unroll
            for (int ks = 0; ks < 2; ++ks) {
                Ah[ks] = *(const bf16x8*)(wrh + (m * 16 + c16) * 64 + ks * 32 + q * 8);
                Al[ks] = *(const bf16x8*)(wrl + (m * 16 + c16) * 64 + ks * 32 + q * 8);
            }
            f32x4 br4 = *(const f32x4*)(brl + m * 16 + q * 4);
#pragma unroll
            for (int nt = 0; nt < 2; ++nt) {
                const int colL = wcol0 + nt * 16 + c16;
                const int wb = colL * 128 + (((m * 2 + (q >> 1)) ^ (colL & 7)) * 16) + (q & 1) * 8;
                u32x2 hh = *(const u32x2*)(smem + HHI_O + wb);
                u32x2 hl = *(const u32x2*)(smem + HLO_O + wb);
                f32x4 c = unpack_add(hh, hl);
#pragma unroll
                for (int i = 0; i < 4; ++i) c[i] += br4[i];
#pragma unroll
                for (int ks = 0; ks < 2; ++ks)
                    c = mm3(Ah[ks], Al[ks], Fh[nt][ks], Fl[nt][ks], c);
                u32x2 ph, pl;
                split_pack(c, ph, pl);
                *(u32x2*)(smem + HHI_O + wb) = ph;
                *(u32x2*)(smem + HLO_O + wb) = pl;
            }
        }
    }

    // ================= post-net =================
    // s = tanh(skip_sum + sum_l bs) -> stage to f planes
#pragma unroll
    for (int m = 0; m < 4; ++m) {
        f32x4 bsum = (f32x4){0.f, 0.f, 0.f, 0.f};
#pragma unroll
        for (int l = 0; l < NL; ++l) {
            f32x4 bv = *(const f32x4*)(bs + l * 64 + m * 16 + q * 4);
#pragma unroll
            for (int i = 0; i < 4; ++i) bsum[i] += bv[i];
        }
#pragma unroll
        for (int nt = 0; nt < 2; ++nt) {
            f32x4 sv;
#pragma unroll
            for (int i = 0; i < 4; ++i) sv[i] = fast_tanh(skipacc[m][nt][i] + bsum[i]);
            const int colL = wcol0 + nt * 16 + c16;
            u32x2 ph, pl;
            split_pack(sv, ph, pl);
            const int wb = colL * 128 + (((m * 2 + (q >> 1)) ^ (colL & 7)) * 16) + (q & 1) * 8;
            *(u32x2*)(smem + FHI_O + wb) = ph;
            *(u32x2*)(smem + FLO_O + wb) = pl;
        }
    }

    // s2 = tanh(W1 s + b1), kept in registers
    bf16x8 Sh[2][2], Sl[2][2];
#pragma unroll
    for (int nt = 0; nt < 2; ++nt) {
        const int colL = wcol0 + nt * 16 + c16;
#pragma unroll
        for (int ks = 0; ks < 2; ++ks) {
            const int sw = colL * 128 + (((ks * 4 + q) ^ (colL & 7)) * 16);
            Sh[nt][ks] = *(const bf16x8*)(smem + FHI_O + sw);
            Sl[nt][ks] = *(const bf16x8*)(smem + FLO_O + sw);
        }
    }
    f32x4 s2a[4][2];
#pragma unroll
    for (int m = 0; m < 4; ++m) {
        bf16x8 Ah[2], Al[2];
#pragma unroll
        for (int ks = 0; ks < 2; ++ks) {
            Ah[ks] = *(const bf16x8*)(wsu + W1HI + (m * 16 + c16) * 64 + ks * 32 + q * 8);
            Al[ks] = *(const bf16x8*)(wsu + W1LO + (m * 16 + c16) * 64 + ks * 32 + q * 8);
        }
        f32x4 b14 = *(const f32x4*)(b1 + m * 16 + q * 4);
#pragma unroll
        for (int nt = 0; nt < 2; ++nt) {
            f32x4 acc = b14;
#pragma unroll
            for (int ks = 0; ks < 2; ++ks)
                acc = mm3(Ah[ks], Al[ks], Sh[nt][ks], Sl[nt][ks], acc);
#pragma unroll
            for (int i = 0; i < 4; ++i) s2a[m][nt][i] = fast_tanh(acc[i]);
        }
    }

    // out = w2 . s2 + b2 : per-lane partial over its 16 rows, reduce across quarter-groups
    f32x4 w24[4];
#pragma unroll
    for (int m = 0; m < 4; ++m) w24[m] = *(const f32x4*)(w2 + m * 16 + q * 4);
    const float b2v = b2[0];
#pragma unroll
    for (int nt = 0; nt < 2; ++nt) {
        float p = 0.0f;
#pragma unroll
        for (int m = 0; m < 4; ++m)
#pragma unroll
            for (int i = 0; i < 4; ++i)
                p = fmaf(w24[m][i], s2a[m][nt][i], p);
        p += __shfl_xor(p, 16);
        p += __shfl_xor(p, 32);
        if (q == 0)
            out[gcol0 + wcol0 + nt * 16 + c16] = b2v + p;
    }
}

extern "C" void kernel_launch(void* const* d_in, const int* in_sizes, int n_in,
                              void* d_out, int out_size, void* d_ws, size_t ws_size,
                              hipStream_t stream) {
    const float* x  = (const float*)d_in[0];
    const float* wc = (const float*)d_in[1];
    const float* bc = (const float*)d_in[2];
    const float* wd = (const float*)d_in[3];
    const float* bd = (const float*)d_in[4];
    const float* wr = (const float*)d_in[5];
    const float* br = (const float*)d_in[6];
    const float* ws = (const float*)d_in[7];
    const float* bs = (const float*)d_in[8];
    const float* w1 = (const float*)d_in[9];
    const float* b1 = (const float*)d_in[10];
    const float* w2 = (const float*)d_in[11];
    const float* b2 = (const float*)d_in[12];
    float* out = (float*)d_out;
    unsigned short* wsu = (unsigned short*)d_ws;

    hipLaunchKernelGGL(wavenet_prep, dim3(1000), dim3(256), 0, stream,
                       wc, wd, ws, wr, w1, wsu);
    hipLaunchKernelGGL(wavenet_mfma, dim3((NB * NT) / 128), dim3(256), 0, stream,
                       x, bc, bd, br, bs, b1, w2, b2, wsu, out);
}